// Round 1
// baseline (230.765 us; speedup 1.0000x reference)
//
#include <hip/hip_runtime.h>
#include <hip/hip_bf16.h>
#include <math.h>

// Problem constants
#define Bn 32
#define Vn 512
#define Kn 16
#define Dn 128
#define En 32
#define NEn 8192
#define BV (Bn*Vn)          // 16384 vertices
#define XSTR 168            // LDS row stride for X tile (160 + 8 pad)
#define ZSTR 264            // LDS row stride for Z tile (256 + 8 pad)
#define SSTR 136            // LDS row stride for support tile (128 + 8 pad)

typedef __bf16 bf16x8 __attribute__((ext_vector_type(8)));
typedef float f32x4 __attribute__((ext_vector_type(4)));
typedef unsigned short ushort4v __attribute__((ext_vector_type(4)));
typedef unsigned short ushort8v __attribute__((ext_vector_type(8)));

union FragU { ushort8v u; bf16x8 b; };

static __device__ inline unsigned short f2bf(float f){
  unsigned u = __float_as_uint(f);
  u += 0x7fffu + ((u >> 16) & 1u);   // round-to-nearest-even
  return (unsigned short)(u >> 16);
}
static __device__ inline ushort4v pack4(float4 v){
  ushort4v r; r.x = f2bf(v.x); r.y = f2bf(v.y); r.z = f2bf(v.z); r.w = f2bf(v.w);
  return r;
}

// ---------------- prep: cast W1/W2/W3 to bf16 in ws ----------------
__global__ void prep_kernel(const float* __restrict__ W1, const float* __restrict__ W2,
                            const float* __restrict__ W3,
                            unsigned short* __restrict__ w1o, unsigned short* __restrict__ w2o,
                            unsigned short* __restrict__ w3o){
  int t = blockIdx.x * 256 + threadIdx.x;
  if (t < 20480)       w1o[t]         = f2bf(W1[t]);
  else if (t < 53248)  w2o[t - 20480] = f2bf(W2[t - 20480]);
  else if (t < 69632)  w3o[t - 53248] = f2bf(W3[t - 53248]);
}

// ---------------- stage 1: gather + W1 GEMM + GELU + masked K-sum ----------------
// grid 1024 x 256thr. Block = 16 vertices, wave = 4 vertices (2 pairs).
__global__ __launch_bounds__(256) void stage1_kernel(
    const float* __restrict__ vf, const int* __restrict__ aadj, const int* __restrict__ badj,
    const float* __restrict__ edge, const float* __restrict__ nbs,
    const unsigned short* __restrict__ w1bf, const float* __restrict__ b1,
    unsigned short* __restrict__ nl_out)
{
  __shared__ __align__(16) unsigned short x_lds[4][2 * 16 * XSTR];
  const int wid  = threadIdx.x >> 6;
  const int lane = threadIdx.x & 63;
  const int col  = lane & 15;
  const int quad = lane >> 4;
  unsigned short* xw = x_lds[wid];

  float b1v[8];
#pragma unroll
  for (int nc = 0; nc < 8; nc++) b1v[nc] = b1[nc * 16 + col];

  const int krow = lane >> 2;   // 0..15: neighbor row this lane stages
  const int part = lane & 3;    // 0..3 : quarter of the row

  for (int it = 0; it < 2; ++it){
    const int bv0 = blockIdx.x * 16 + wid * 4 + it * 2;   // vertex pair base
    // ---- stage X = [vn | en] for 2 vertices into LDS (bf16) ----
#pragma unroll
    for (int pv = 0; pv < 2; ++pv){
      const int bv = bv0 + pv;
      const int a = aadj[bv * Kn + krow];
      const int e = badj[bv * Kn + krow];
      unsigned short* row = xw + pv * 16 * XSTR + krow * XSTR;
      const float4* vsrc = (const float4*)(vf + (size_t)a * Dn);
#pragma unroll
      for (int i = 0; i < 8; i++){
        float4 v = vsrc[part * 8 + i];
        *(ushort4v*)(row + part * 32 + i * 4) = pack4(v);
      }
      const float4* esrc = (const float4*)(edge + (size_t)e * En);
#pragma unroll
      for (int i = 0; i < 2; i++){
        float4 v = esrc[part * 2 + i];
        *(ushort4v*)(row + 128 + part * 8 + i * 4) = pack4(v);
      }
    }
    __syncthreads();

    // ---- Y = X @ W1^T via MFMA; A[m][k]: m=col, k=quad*8+j; B[k][n]=W1[n][k] ----
    f32x4 acc0[8] = {};
    f32x4 acc1[8] = {};
#pragma unroll
    for (int kc = 0; kc < 5; kc++){
      FragU a0, a1;
      a0.u = *(const ushort8v*)(xw + col * XSTR + kc * 32 + quad * 8);
      a1.u = *(const ushort8v*)(xw + 16 * XSTR + col * XSTR + kc * 32 + quad * 8);
#pragma unroll
      for (int nc = 0; nc < 8; nc++){
        FragU bf_;
        bf_.u = *(const ushort8v*)(w1bf + (nc * 16 + col) * 160 + kc * 32 + quad * 8);
        acc0[nc] = __builtin_amdgcn_mfma_f32_16x16x32_bf16(a0.b, bf_.b, acc0[nc], 0, 0, 0);
        acc1[nc] = __builtin_amdgcn_mfma_f32_16x16x32_bf16(a1.b, bf_.b, acc1[nc], 0, 0, 0);
      }
    }

    // ---- epilogue: +b1, exact GELU, nbs_mask weight, reduce over 16 neighbors ----
#pragma unroll
    for (int pv = 0; pv < 2; ++pv){
      const int bv = bv0 + pv;
      float mk[4];
#pragma unroll
      for (int r = 0; r < 4; r++) mk[r] = nbs[bv * Kn + quad * 4 + r];
#pragma unroll
      for (int nc = 0; nc < 8; nc++){
        f32x4 acc = (pv == 0) ? acc0[nc] : acc1[nc];
        float s = 0.f;
#pragma unroll
        for (int r = 0; r < 4; r++){
          float y = acc[r] + b1v[nc];                       // Y[m=quad*4+r][d=nc*16+col]
          float g = 0.5f * y * (1.f + erff(y * 0.70710678118654752f)); // exact GELU
          s += g * mk[r];
        }
        s += __shfl_xor(s, 16, 64);   // reduce across quads (neighbor groups)
        s += __shfl_xor(s, 32, 64);
        if ((nc >> 1) == quad){       // quad q writes nc = 2q, 2q+1
          nl_out[bv * Dn + nc * 16 + col] = f2bf(s);
        }
      }
    }
    __syncthreads();
  }
}

// ---------------- stage 2/3: W2, support, W3, final combine ----------------
// grid 256 x 256thr. Wave = 16 vertices.
__global__ __launch_bounds__(256) void stage2_kernel(
    const float* __restrict__ vf, const float* __restrict__ h0,
    const unsigned short* __restrict__ nl_in,
    const unsigned short* __restrict__ w2bf, const unsigned short* __restrict__ w3bf,
    const float* __restrict__ b2, const float* __restrict__ b3,
    const float* __restrict__ lamda, const float* __restrict__ alpha,
    const int* __restrict__ lval,
    float* __restrict__ out)
{
  __shared__ __align__(16) unsigned short z_lds[4][16 * ZSTR];
  __shared__ __align__(16) unsigned short s_lds[4][16 * SSTR];
  const int wid  = threadIdx.x >> 6;
  const int lane = threadIdx.x & 63;
  const int col  = lane & 15;
  const int quad = lane >> 4;
  const int vb   = (blockIdx.x * 4 + wid) * 16;
  const float th = logf(lamda[0] / (float)lval[0] + 1.0f);
  const float al = alpha[0];

  // ---- stage Z = [nl | vf] (16 x 256) into LDS bf16 ----
  {
    const int m = lane >> 2, q = lane & 3;
    unsigned short* zrow = z_lds[wid] + m * ZSTR + q * 64;
    if (q < 2){
      const ushort4v* src = (const ushort4v*)(nl_in + (size_t)(vb + m) * Dn + q * 64);
#pragma unroll
      for (int j = 0; j < 16; j++) *(ushort4v*)(zrow + j * 4) = src[j];
    } else {
      const float4* src = (const float4*)(vf + (size_t)(vb + m) * Dn + (q - 2) * 64);
#pragma unroll
      for (int j = 0; j < 16; j++) *(ushort4v*)(zrow + j * 4) = pack4(src[j]);
    }
  }
  __syncthreads();

  // ---- hi = Z @ W2^T ----
  f32x4 acc2[8] = {};
#pragma unroll
  for (int kc = 0; kc < 8; kc++){
    FragU a;
    a.u = *(const ushort8v*)(z_lds[wid] + col * ZSTR + kc * 32 + quad * 8);
#pragma unroll
    for (int nc = 0; nc < 8; nc++){
      FragU bf_;
      bf_.u = *(const ushort8v*)(w2bf + (nc * 16 + col) * 256 + kc * 32 + quad * 8);
      acc2[nc] = __builtin_amdgcn_mfma_f32_16x16x32_bf16(a.b, bf_.b, acc2[nc], 0, 0, 0);
    }
  }

  // ---- support = (1-alpha)*(hi+b2) + alpha*h0 ; keep fp32, stage bf16 to LDS ----
  float sup[8][4];
#pragma unroll
  for (int nc = 0; nc < 8; nc++){
    const int d = nc * 16 + col;
    const float bb = b2[d];
#pragma unroll
    for (int r = 0; r < 4; r++){
      const int vtx = vb + quad * 4 + r;
      float hi = acc2[nc][r] + bb;
      float s = (1.f - al) * hi + al * h0[(size_t)vtx * Dn + d];
      sup[nc][r] = s;
      s_lds[wid][(quad * 4 + r) * SSTR + d] = f2bf(s);
    }
  }
  __syncthreads();

  // ---- out3 = support @ W3^T ----
  f32x4 acc3[8] = {};
#pragma unroll
  for (int kc = 0; kc < 4; kc++){
    FragU a;
    a.u = *(const ushort8v*)(s_lds[wid] + col * SSTR + kc * 32 + quad * 8);
#pragma unroll
    for (int nc = 0; nc < 8; nc++){
      FragU bf_;
      bf_.u = *(const ushort8v*)(w3bf + (nc * 16 + col) * 128 + kc * 32 + quad * 8);
      acc3[nc] = __builtin_amdgcn_mfma_f32_16x16x32_bf16(a.b, bf_.b, acc3[nc], 0, 0, 0);
    }
  }

  // ---- out = theta*(out3+b3) + (1-theta)*support + vf ----
#pragma unroll
  for (int nc = 0; nc < 8; nc++){
    const int d = nc * 16 + col;
    const float bb = b3[d];
#pragma unroll
    for (int r = 0; r < 4; r++){
      const int vtx = vb + quad * 4 + r;
      float o = th * (acc3[nc][r] + bb) + (1.f - th) * sup[nc][r]
              + vf[(size_t)vtx * Dn + d];
      out[(size_t)vtx * Dn + d] = o;
    }
  }
}

extern "C" void kernel_launch(void* const* d_in, const int* in_sizes, int n_in,
                              void* d_out, int out_size, void* d_ws, size_t ws_size,
                              hipStream_t stream)
{
  const float* vfp  = (const float*)d_in[0];
  const int*   aadj = (const int*)d_in[1];
  const int*   badj = (const int*)d_in[2];
  const float* h0   = (const float*)d_in[3];
  const float* lam  = (const float*)d_in[4];
  const float* alp  = (const float*)d_in[5];
  const int*   lv   = (const int*)d_in[6];
  const float* edge = (const float*)d_in[7];
  // d_in[8] vertex_mask: unused by the reference math
  const float* nbs  = (const float*)d_in[9];
  const float* W1   = (const float*)d_in[10];
  const float* b1   = (const float*)d_in[11];
  const float* W2   = (const float*)d_in[12];
  const float* b2   = (const float*)d_in[13];
  const float* W3   = (const float*)d_in[14];
  const float* b3   = (const float*)d_in[15];
  float* out = (float*)d_out;

  // ws layout (bytes): [0,40960) w1bf | [40960,106496) w2bf | [106496,139264) w3bf
  //                    | [139264, 139264+4194304) nl bf16
  unsigned short* w1bf = (unsigned short*)d_ws;
  unsigned short* w2bf = w1bf + 20480;
  unsigned short* w3bf = w2bf + 32768;
  unsigned short* nlbf = (unsigned short*)((char*)d_ws + 139264);

  prep_kernel<<<272, 256, 0, stream>>>(W1, W2, W3, w1bf, w2bf, w3bf);
  stage1_kernel<<<1024, 256, 0, stream>>>(vfp, aadj, badj, edge, nbs, w1bf, b1, nlbf);
  stage2_kernel<<<256, 256, 0, stream>>>(vfp, h0, nlbf, w2bf, w3bf, b2, b3, lam, alp, lv, out);
}